// Round 3
// baseline (207.782 us; speedup 1.0000x reference)
//
#include <hip/hip_runtime.h>
#include <hip/hip_bf16.h>

// Problem constants
#define BH 96      // B*H
#define TOK 2048   // B*N
#define THW 24576  // B*H*N

typedef unsigned short ushort_t;
typedef __attribute__((ext_vector_type(8))) short short8;
typedef __attribute__((ext_vector_type(4))) float f32x4;

static __device__ __forceinline__ float bf2f(ushort_t u){
  union { unsigned int i; float f; } t; t.i = ((unsigned int)u)<<16; return t.f;
}
static __device__ __forceinline__ ushort_t f2bf(float f){
  union { float f; unsigned int i; } t; t.f = f;
  unsigned int u = t.i;
  return (ushort_t)((u + 0x7fffu + ((u>>16)&1u)) >> 16);
}
static __device__ __forceinline__ short8 pack8(f32x4 a, f32x4 b){
  short8 r;
  #pragma unroll
  for (int j=0;j<4;++j){ r[j]=(short)f2bf(a[j]); r[4+j]=(short)f2bf(b[j]); }
  return r;
}
static __device__ __forceinline__ float gelu_exact(float x){
  return 0.5f*x*(1.0f + erff(x*0.70710678118654752f));
}

// ---------------------------------------------------------------------------
// K0: pack wgt[e][k] (e<64, k<4160): k<4096 -> w_g[(d*64+e)*64+c] (k=d*64+c)
//                                    k>=4096 -> w_bg[e*64 + (k-4096)]
__global__ void k_packwgt(const float* __restrict__ w_g,
                          const float* __restrict__ w_bg,
                          ushort_t* __restrict__ wgt){
  int i = blockIdx.x*256 + threadIdx.x;
  if (i >= 64*4160) return;
  int e = i/4160, k = i - e*4160;
  float v;
  if (k < 4096){ int d = k>>6, c = k&63; v = w_g[(d*64+e)*64 + c]; }
  else         { v = w_bg[e*64 + (k-4096)]; }
  wgt[i] = f2bf(v);
}

// ---------------------------------------------------------------------------
// K1: fused projection GEMM  Y = x @ Wcat^T + b   (M=2048, N=3840, K=768)
// cols [0,2304): qkv -> qb (scaled 1/8), kb, vb  in [bh][n][d] bf16
// cols [2304,3072): li = gelu(...) -> lib ; [3072,3840): gi -> gib
__global__ __launch_bounds__(256) void k_proj(
    const float* __restrict__ x,
    const float* __restrict__ w_qkv, const float* __restrict__ b_qkv,
    const float* __restrict__ w_local, const float* __restrict__ b_local,
    const float* __restrict__ w_global, const float* __restrict__ b_global,
    ushort_t* __restrict__ qb, ushort_t* __restrict__ kb, ushort_t* __restrict__ vb,
    ushort_t* __restrict__ lib, ushort_t* __restrict__ gib)
{
  __shared__ ushort_t As[64*40];
  __shared__ ushort_t Bs[64*40];
  const int n0 = blockIdx.x*64;
  const int m0 = blockIdx.y*64;
  const float* wsrc; const float* bsrc; int nb, seg;
  if (n0 < 2304){ wsrc=w_qkv;   bsrc=b_qkv;   nb=n0;      seg=0; }
  else if (n0 < 3072){ wsrc=w_local;  bsrc=b_local;  nb=n0-2304; seg=1; }
  else {               wsrc=w_global; bsrc=b_global; nb=n0-3072; seg=2; }
  const int t = threadIdx.x;
  const int w = t>>6, l = t&63;
  const int wr = w>>1, wc = w&1;
  const int rA = t>>2, cA = (t&3)*8;
  const int lr = l&15, lk = (l>>4)*8;
  f32x4 acc00={0,0,0,0}, acc01={0,0,0,0}, acc10={0,0,0,0}, acc11={0,0,0,0};
  for (int k0=0; k0<768; k0+=32){
    const float* xp = x    + (size_t)(m0+rA)*768 + k0 + cA;
    const float* wp = wsrc + (size_t)(nb+rA)*768 + k0 + cA;
    short8 ga = pack8(*(const f32x4*)(xp), *(const f32x4*)(xp+4));
    short8 gb = pack8(*(const f32x4*)(wp), *(const f32x4*)(wp+4));
    __syncthreads();
    *(short8*)(As + rA*40 + cA) = ga;
    *(short8*)(Bs + rA*40 + cA) = gb;
    __syncthreads();
    short8 a0 = *(const short8*)(As + (wr*32 +      lr)*40 + lk);
    short8 a1 = *(const short8*)(As + (wr*32 + 16 + lr)*40 + lk);
    short8 b0 = *(const short8*)(Bs + (wc*32 +      lr)*40 + lk);
    short8 b1 = *(const short8*)(Bs + (wc*32 + 16 + lr)*40 + lk);
    acc00 = __builtin_amdgcn_mfma_f32_16x16x32_bf16(a0,b0,acc00,0,0,0);
    acc01 = __builtin_amdgcn_mfma_f32_16x16x32_bf16(a0,b1,acc01,0,0,0);
    acc10 = __builtin_amdgcn_mfma_f32_16x16x32_bf16(a1,b0,acc10,0,0,0);
    acc11 = __builtin_amdgcn_mfma_f32_16x16x32_bf16(a1,b1,acc11,0,0,0);
  }
  #pragma unroll
  for (int fm=0; fm<2; ++fm){
    #pragma unroll
    for (int fn=0; fn<2; ++fn){
      f32x4 acc = (fm==0) ? ((fn==0)?acc00:acc01) : ((fn==0)?acc10:acc11);
      #pragma unroll
      for (int r=0; r<4; ++r){
        int grow = m0 + wr*32 + fm*16 + (l>>4)*4 + r;
        int colLoc = nb + wc*32 + fn*16 + lr;
        float val = acc[r] + bsrc[colLoc];
        int b = grow>>8, n = grow&255;
        if (seg==0){
          int s = colLoc/768, rr = colLoc - s*768;
          int h = rr>>6, d = rr&63;
          size_t idx = ((size_t)(b*12+h)*256 + n)*64 + d;
          if (s==0)      qb[idx] = f2bf(val*0.125f);
          else if (s==1) kb[idx] = f2bf(val);
          else           vb[idx] = f2bf(val);
        } else {
          int h = colLoc>>6, d = colLoc&63;
          size_t idx = ((size_t)(b*12+h)*256 + n)*64 + d;
          ushort_t gv = f2bf(gelu_exact(val));
          if (seg==1) lib[idx] = gv; else gib[idx] = gv;
        }
      }
    }
  }
}

// ---------------------------------------------------------------------------
// K2: transpose [bh][m][e] -> [bh][e][m] for v and gi
__global__ __launch_bounds__(256) void k_transpose(
    const ushort_t* __restrict__ vb, const ushort_t* __restrict__ gib,
    ushort_t* __restrict__ vT, ushort_t* __restrict__ giT)
{
  int bh = blockIdx.x;
  const ushort_t* src = blockIdx.y ? gib : vb;
  ushort_t* dst       = blockIdx.y ? giT : vT;
  __shared__ ushort_t tile[256*72];
  int t = threadIdx.x;
  for (int i=t; i<2048; i+=256){
    int m = i>>3, e0 = (i&7)*8;
    *(short8*)(tile + m*72 + e0) =
      *(const short8*)(src + ((size_t)bh*256 + m)*64 + e0);
  }
  __syncthreads();
  for (int i=t; i<2048; i+=256){
    int e = i>>5, m0 = (i&31)*8;
    short8 v;
    #pragma unroll
    for (int j=0;j<8;++j) v[j] = (short)tile[(m0+j)*72 + e];
    *(short8*)(dst + ((size_t)bh*64 + e)*256 + m0) = v;
  }
}

// ---------------------------------------------------------------------------
// K3a: S = q @ k^T (q pre-scaled), plus row max / row expsum
__global__ __launch_bounds__(256) void k_logits(
    const ushort_t* __restrict__ qb, const ushort_t* __restrict__ kb,
    float* __restrict__ S, float* __restrict__ rmaxb, float* __restrict__ rsumb)
{
  int bh = blockIdx.x, n0 = blockIdx.y*64;
  int t = threadIdx.x, w = t>>6, l = t&63;
  int lr = l&15, lk = (l>>4)*8;
  int row = n0 + w*16 + lr;
  const ushort_t* qp = qb + ((size_t)bh*256 + row)*64 + lk;
  short8 a0 = *(const short8*)(qp);
  short8 a1 = *(const short8*)(qp + 32);
  f32x4 acc[16];
  #pragma unroll
  for (int f=0; f<16; ++f) acc[f] = (f32x4){0,0,0,0};
  #pragma unroll
  for (int f=0; f<16; ++f){
    int col = f*16 + lr;
    const ushort_t* kp = kb + ((size_t)bh*256 + col)*64 + lk;
    short8 b0 = *(const short8*)(kp);
    short8 b1 = *(const short8*)(kp + 32);
    acc[f] = __builtin_amdgcn_mfma_f32_16x16x32_bf16(a0,b0,acc[f],0,0,0);
    acc[f] = __builtin_amdgcn_mfma_f32_16x16x32_bf16(a1,b1,acc[f],0,0,0);
  }
  #pragma unroll
  for (int r=0; r<4; ++r){
    int n = n0 + w*16 + (l>>4)*4 + r;
    float mx = acc[0][r];
    #pragma unroll
    for (int f=1; f<16; ++f) mx = fmaxf(mx, acc[f][r]);
    mx = fmaxf(mx, __shfl_xor(mx, 1));
    mx = fmaxf(mx, __shfl_xor(mx, 2));
    mx = fmaxf(mx, __shfl_xor(mx, 4));
    mx = fmaxf(mx, __shfl_xor(mx, 8));
    float sm = 0.f;
    #pragma unroll
    for (int f=0; f<16; ++f) sm += __expf(acc[f][r] - mx);
    sm += __shfl_xor(sm, 1);
    sm += __shfl_xor(sm, 2);
    sm += __shfl_xor(sm, 4);
    sm += __shfl_xor(sm, 8);
    #pragma unroll
    for (int f=0; f<16; ++f)
      S[((size_t)bh*256 + n)*256 + f*16 + lr] = acc[f][r];
    if (lr == 0){ rmaxb[bh*256+n] = mx; rsumb[bh*256+n] = sm; }
  }
}

// ---------------------------------------------------------------------------
// K3b: column stats over n for each m
__global__ __launch_bounds__(256) void k_colstats(
    const float* __restrict__ S, float* __restrict__ cmaxb, float* __restrict__ csumb)
{
  int bh = blockIdx.x, m0 = blockIdx.y*64;
  int t = threadIdx.x, q = t>>6, ml = t&63;
  int m = m0 + ml;
  float mx = -1e30f, sm = 0.f;
  for (int n=q*64; n<q*64+64; ++n){
    float v = S[((size_t)bh*256 + n)*256 + m];
    float nm = fmaxf(mx, v);
    sm = sm*__expf(mx-nm) + __expf(v-nm);
    mx = nm;
  }
  __shared__ float smx[4][64], ssm[4][64];
  smx[q][ml] = mx; ssm[q][ml] = sm;
  __syncthreads();
  if (t < 64){
    float M = smx[0][t];
    #pragma unroll
    for (int qq=1; qq<4; ++qq) M = fmaxf(M, smx[qq][t]);
    float Ssum = 0.f;
    #pragma unroll
    for (int qq=0; qq<4; ++qq) Ssum += ssm[qq][t]*__expf(smx[qq][t]-M);
    cmaxb[bh*256 + m0 + t] = M;
    csumb[bh*256 + m0 + t] = Ssum;
  }
}

// ---------------------------------------------------------------------------
// K3c: sa = attn @ v -> saf[B,N,C] (f32), gs = rattn @ gi -> gsb bf16
__global__ __launch_bounds__(256) void k_attnmm(
    const float* __restrict__ S,
    const float* __restrict__ rmaxb, const float* __restrict__ rsumb,
    const float* __restrict__ cmaxb, const float* __restrict__ csumb,
    const ushort_t* __restrict__ vT, const ushort_t* __restrict__ giT,
    ushort_t* __restrict__ gsb, float* __restrict__ saf)
{
  int bh = blockIdx.x, n0 = blockIdx.y*64;
  int b = bh/12, h = bh - b*12;
  int t = threadIdx.x, w = t>>6, l = t&63;
  int lr = l&15;
  int n = n0 + w*16 + lr;   // A-fragment row
  float rmx = rmaxb[bh*256 + n];
  f32x4 asa[4], ags[4];
  #pragma unroll
  for (int fn=0; fn<4; ++fn){ asa[fn]=(f32x4){0,0,0,0}; ags[fn]=(f32x4){0,0,0,0}; }
  #pragma unroll
  for (int kk=0; kk<8; ++kk){
    int mbase = kk*32 + (l>>4)*8;
    const float* Sp = S + ((size_t)bh*256 + n)*256 + mbase;
    f32x4 s_lo = *(const f32x4*)(Sp);
    f32x4 s_hi = *(const f32x4*)(Sp+4);
    f32x4 cm_lo = *(const f32x4*)(cmaxb + bh*256 + mbase);
    f32x4 cm_hi = *(const f32x4*)(cmaxb + bh*256 + mbase + 4);
    f32x4 cs_lo = *(const f32x4*)(csumb + bh*256 + mbase);
    f32x4 cs_hi = *(const f32x4*)(csumb + bh*256 + mbase + 4);
    short8 a_at, a_rat;
    #pragma unroll
    for (int j=0;j<4;++j){
      a_at[j]    = (short)f2bf(__expf(s_lo[j] - rmx));
      a_at[j+4]  = (short)f2bf(__expf(s_hi[j] - rmx));
      a_rat[j]   = (short)f2bf(__expf(s_lo[j] - cm_lo[j]) / cs_lo[j]);
      a_rat[j+4] = (short)f2bf(__expf(s_hi[j] - cm_hi[j]) / cs_hi[j]);
    }
    #pragma unroll
    for (int fn=0; fn<4; ++fn){
      int e = fn*16 + lr;
      short8 bv = *(const short8*)(vT  + ((size_t)bh*64 + e)*256 + mbase);
      short8 bg = *(const short8*)(giT + ((size_t)bh*64 + e)*256 + mbase);
      asa[fn] = __builtin_amdgcn_mfma_f32_16x16x32_bf16(a_at,  bv, asa[fn],0,0,0);
      ags[fn] = __builtin_amdgcn_mfma_f32_16x16x32_bf16(a_rat, bg, ags[fn],0,0,0);
    }
  }
  #pragma unroll
  for (int r=0; r<4; ++r){
    int nr = n0 + w*16 + (l>>4)*4 + r;
    float rs = rsumb[bh*256 + nr];
    #pragma unroll
    for (int fn=0; fn<4; ++fn){
      int e = fn*16 + lr;
      saf[((size_t)(b*256 + nr))*768 + h*64 + e] = asa[fn][r] / rs;
      gsb[((size_t)bh*256 + nr)*64 + e] = f2bf(ags[fn][r]);
    }
  }
}

// ---------------------------------------------------------------------------
// K4: ISA = U @ Wg2 (+ gs @ w_bg^T fused as K tail). M=24576, N=64, K=4160
__global__ __launch_bounds__(256) void k_isa(
    const ushort_t* __restrict__ lib, const ushort_t* __restrict__ gib,
    const ushort_t* __restrict__ gsb, const ushort_t* __restrict__ wgt,
    float* __restrict__ isaf)
{
  __shared__ ushort_t As[64*40];
  __shared__ ushort_t Bs[64*40];
  const int t0 = blockIdx.x*64;
  const int t = threadIdx.x, w = t>>6, l = t&63;
  const int wr = w>>1, wc = w&1;
  const int rA = t>>2, cA = (t&3)*8;
  const int lr = l&15, lk = (l>>4)*8;
  f32x4 acc00={0,0,0,0}, acc01={0,0,0,0}, acc10={0,0,0,0}, acc11={0,0,0,0};
  for (int kb=0; kb<130; ++kb){
    short8 ub = *(const short8*)(wgt + (size_t)rA*4160 + kb*32 + cA);
    short8 ua;
    if (kb < 128){
      int d = kb>>1, c0 = (kb&1)*32;
      float liv = bf2f(lib[((size_t)t0+rA)*64 + d]);
      short8 g8 = *(const short8*)(gib + ((size_t)t0+rA)*64 + c0 + cA);
      #pragma unroll
      for (int j=0;j<8;++j) ua[j] = (short)f2bf(liv * bf2f((ushort_t)g8[j]));
    } else {
      ua = *(const short8*)(gsb + ((size_t)t0+rA)*64 + (kb-128)*32 + cA);
    }
    __syncthreads();
    *(short8*)(As + rA*40 + cA) = ua;
    *(short8*)(Bs + rA*40 + cA) = ub;
    __syncthreads();
    short8 a0 = *(const short8*)(As + (wr*32 +      lr)*40 + lk);
    short8 a1 = *(const short8*)(As + (wr*32 + 16 + lr)*40 + lk);
    short8 b0 = *(const short8*)(Bs + (wc*32 +      lr)*40 + lk);
    short8 b1 = *(const short8*)(Bs + (wc*32 + 16 + lr)*40 + lk);
    acc00 = __builtin_amdgcn_mfma_f32_16x16x32_bf16(a0,b0,acc00,0,0,0);
    acc01 = __builtin_amdgcn_mfma_f32_16x16x32_bf16(a0,b1,acc01,0,0,0);
    acc10 = __builtin_amdgcn_mfma_f32_16x16x32_bf16(a1,b0,acc10,0,0,0);
    acc11 = __builtin_amdgcn_mfma_f32_16x16x32_bf16(a1,b1,acc11,0,0,0);
  }
  #pragma unroll
  for (int fm=0; fm<2; ++fm){
    #pragma unroll
    for (int fn=0; fn<2; ++fn){
      f32x4 acc = (fm==0) ? ((fn==0)?acc00:acc01) : ((fn==0)?acc10:acc11);
      #pragma unroll
      for (int r=0; r<4; ++r){
        int tok = t0 + wr*32 + fm*16 + (l>>4)*4 + r;
        int e = wc*32 + fn*16 + lr;
        int bh = tok>>8, n = tok&255;
        int b = bh/12, h = bh - b*12;
        isaf[((size_t)(b*256 + n))*768 + h*64 + e] = acc[r];
      }
    }
  }
}

// ---------------------------------------------------------------------------
// K5: per-token LayerNorm(sa), LayerNorm(isa), gated mix -> zb bf16
__global__ __launch_bounds__(256) void k_lnmix(
    const float* __restrict__ saf, const float* __restrict__ isaf,
    const float* __restrict__ lam, ushort_t* __restrict__ zb)
{
  int tok = blockIdx.x*4 + (threadIdx.x>>6);
  int l = threadIdx.x & 63;
  float g = 1.f/(1.f + __expf(-lam[0]));
  const float* sp = saf  + (size_t)tok*768;
  const float* ip = isaf + (size_t)tok*768;
  float sv[12], iv[12];
  float s1=0.f, s2=0.f, i1=0.f, i2=0.f;
  #pragma unroll
  for (int j=0;j<12;++j){
    sv[j] = sp[l + j*64];  s1 += sv[j];  s2 += sv[j]*sv[j];
    iv[j] = ip[l + j*64];  i1 += iv[j];  i2 += iv[j]*iv[j];
  }
  #pragma unroll
  for (int m=1; m<64; m<<=1){
    s1 += __shfl_xor(s1, m); s2 += __shfl_xor(s2, m);
    i1 += __shfl_xor(i1, m); i2 += __shfl_xor(i2, m);
  }
  float smean = s1*(1.f/768.f), svar = s2*(1.f/768.f) - smean*smean;
  float imean = i1*(1.f/768.f), ivar = i2*(1.f/768.f) - imean*imean;
  float sinv = 1.f/sqrtf(svar + 1e-5f);
  float iinv = 1.f/sqrtf(ivar + 1e-5f);
  #pragma unroll
  for (int j=0;j<12;++j){
    float z = g*(sv[j]-smean)*sinv + (1.f-g)*(iv[j]-imean)*iinv;
    zb[(size_t)tok*768 + l + j*64] = f2bf(z);
  }
}

// ---------------------------------------------------------------------------
// K6: out = z @ w_proj^T + b_proj  (M=2048, N=768, K=768) -> f32 out
__global__ __launch_bounds__(256) void k_outproj(
    const ushort_t* __restrict__ zb, const float* __restrict__ wproj,
    const float* __restrict__ bproj, float* __restrict__ out)
{
  __shared__ ushort_t As[64*40];
  __shared__ ushort_t Bs[64*40];
  const int n0 = blockIdx.x*64;
  const int m0 = blockIdx.y*64;
  const int t = threadIdx.x, w = t>>6, l = t&63;
  const int wr = w>>1, wc = w&1;
  const int rA = t>>2, cA = (t&3)*8;
  const int lr = l&15, lk = (l>>4)*8;
  f32x4 acc00={0,0,0,0}, acc01={0,0,0,0}, acc10={0,0,0,0}, acc11={0,0,0,0};
  for (int k0=0; k0<768; k0+=32){
    short8 ga = *(const short8*)(zb + (size_t)(m0+rA)*768 + k0 + cA);
    const float* wp = wproj + (size_t)(n0+rA)*768 + k0 + cA;
    short8 gb = pack8(*(const f32x4*)(wp), *(const f32x4*)(wp+4));
    __syncthreads();
    *(short8*)(As + rA*40 + cA) = ga;
    *(short8*)(Bs + rA*40 + cA) = gb;
    __syncthreads();
    short8 a0 = *(const short8*)(As + (wr*32 +      lr)*40 + lk);
    short8 a1 = *(const short8*)(As + (wr*32 + 16 + lr)*40 + lk);
    short8 b0 = *(const short8*)(Bs + (wc*32 +      lr)*40 + lk);
    short8 b1 = *(const short8*)(Bs + (wc*32 + 16 + lr)*40 + lk);
    acc00 = __builtin_amdgcn_mfma_f32_16x16x32_bf16(a0,b0,acc00,0,0,0);
    acc01 = __builtin_amdgcn_mfma_f32_16x16x32_bf16(a0,b1,acc01,0,0,0);
    acc10 = __builtin_amdgcn_mfma_f32_16x16x32_bf16(a1,b0,acc10,0,0,0);
    acc11 = __builtin_amdgcn_mfma_f32_16x16x32_bf16(a1,b1,acc11,0,0,0);
  }
  #pragma unroll
  for (int fm=0; fm<2; ++fm){
    #pragma unroll
    for (int fn=0; fn<2; ++fn){
      f32x4 acc = (fm==0) ? ((fn==0)?acc00:acc01) : ((fn==0)?acc10:acc11);
      #pragma unroll
      for (int r=0; r<4; ++r){
        int grow = m0 + wr*32 + fm*16 + (l>>4)*4 + r;
        int gcol = n0 + wc*32 + fn*16 + lr;
        out[(size_t)grow*768 + gcol] = acc[r] + bproj[gcol];
      }
    }
  }
}

// ---------------------------------------------------------------------------
extern "C" void kernel_launch(void* const* d_in, const int* in_sizes, int n_in,
                              void* d_out, int out_size, void* d_ws, size_t ws_size,
                              hipStream_t stream)
{
  const float* x        = (const float*)d_in[0];
  const float* w_qkv    = (const float*)d_in[1];
  const float* b_qkv    = (const float*)d_in[2];
  const float* w_g      = (const float*)d_in[3];
  const float* w_bg     = (const float*)d_in[4];
  const float* w_local  = (const float*)d_in[5];
  const float* b_local  = (const float*)d_in[6];
  const float* w_globalp= (const float*)d_in[7];
  const float* b_globalp= (const float*)d_in[8];
  const float* lam      = (const float*)d_in[9];
  const float* w_proj   = (const float*)d_in[10];
  const float* b_proj   = (const float*)d_in[11];
  float* out = (float*)d_out;

  char* p = (char*)d_ws;
  auto alloc = [&](size_t bytes)->char*{
    char* r = p; p += (bytes + 255) & ~(size_t)255; return r;
  };
  // Live-range-aware layout (peak ~49 MB):
  ushort_t* wgt = (ushort_t*)alloc((size_t)64*4160*2);
  ushort_t* qb  = (ushort_t*)alloc((size_t)THW*64*2);   // dead after k_logits
  ushort_t* kb  = (ushort_t*)alloc((size_t)THW*64*2);   // dead after k_logits
  ushort_t* vb  = (ushort_t*)alloc((size_t)THW*64*2);   // dead after k_transpose
  ushort_t* vT  = (ushort_t*)alloc((size_t)THW*64*2);   // dead after k_attnmm
  ushort_t* giT = (ushort_t*)alloc((size_t)THW*64*2);   // dead after k_attnmm
  ushort_t* gib = (ushort_t*)alloc((size_t)THW*64*2);
  ushort_t* lib = (ushort_t*)alloc((size_t)THW*64*2);
  ushort_t* gsb = (ushort_t*)alloc((size_t)THW*64*2);
  float*  S     = (float*)  alloc((size_t)BH*256*256*4);
  float*  rmaxb = (float*)  alloc((size_t)BH*256*4);
  float*  rsumb = (float*)  alloc((size_t)BH*256*4);
  float*  cmaxb = (float*)  alloc((size_t)BH*256*4);
  float*  csumb = (float*)  alloc((size_t)BH*256*4);
  // Aliases over dead buffers:
  float*    saf  = (float*)qb;      // 6.29 MB over qb+kb (contiguous)
  float*    isaf = (float*)vT;      // 6.29 MB over vT+giT (contiguous)
  ushort_t* zb   = (ushort_t*)vb;   // 3.15 MB over vb

  hipLaunchKernelGGL(k_packwgt, dim3((64*4160+255)/256), dim3(256), 0, stream,
                     w_g, w_bg, wgt);
  hipLaunchKernelGGL(k_proj, dim3(60,32), dim3(256), 0, stream,
                     x, w_qkv, b_qkv, w_local, b_local, w_globalp, b_globalp,
                     qb, kb, vb, lib, gib);
  hipLaunchKernelGGL(k_transpose, dim3(96,2), dim3(256), 0, stream,
                     vb, gib, vT, giT);
  hipLaunchKernelGGL(k_logits, dim3(96,4), dim3(256), 0, stream,
                     qb, kb, S, rmaxb, rsumb);
  hipLaunchKernelGGL(k_colstats, dim3(96,4), dim3(256), 0, stream,
                     S, cmaxb, csumb);
  hipLaunchKernelGGL(k_attnmm, dim3(96,4), dim3(256), 0, stream,
                     S, rmaxb, rsumb, cmaxb, csumb, vT, giT, gsb, saf);
  hipLaunchKernelGGL(k_isa, dim3(384), dim3(256), 0, stream,
                     lib, gib, gsb, wgt, isaf);
  hipLaunchKernelGGL(k_lnmix, dim3(512), dim3(256), 0, stream,
                     saf, isaf, lam, zb);
  hipLaunchKernelGGL(k_outproj, dim3(12,32), dim3(256), 0, stream,
                     zb, w_proj, b_proj, out);
}

// Round 4
// 169.543 us; speedup vs baseline: 1.2255x; 1.2255x over previous
//
#include <hip/hip_runtime.h>
#include <hip/hip_bf16.h>

// Problem constants
#define BH 96      // B*H
#define TOK 2048   // B*N
#define THW 24576  // B*H*N

typedef unsigned short ushort_t;
typedef __attribute__((ext_vector_type(8))) short short8;
typedef __attribute__((ext_vector_type(4))) float f32x4;

static __device__ __forceinline__ float bf2f(ushort_t u){
  union { unsigned int i; float f; } t; t.i = ((unsigned int)u)<<16; return t.f;
}
static __device__ __forceinline__ ushort_t f2bf(float f){
  union { float f; unsigned int i; } t; t.f = f;
  unsigned int u = t.i;
  return (ushort_t)((u + 0x7fffu + ((u>>16)&1u)) >> 16);
}
static __device__ __forceinline__ short8 pack8(f32x4 a, f32x4 b){
  short8 r;
  #pragma unroll
  for (int j=0;j<4;++j){ r[j]=(short)f2bf(a[j]); r[4+j]=(short)f2bf(b[j]); }
  return r;
}
static __device__ __forceinline__ float gelu_exact(float x){
  return 0.5f*x*(1.0f + erff(x*0.70710678118654752f));
}
// 8 f32 scaled by s -> bf16x8 (RNE via v_cvt_pk_bf16_f32)
static __device__ __forceinline__ short8 mulpack8(const float* f, float s){
  union { short8 s8; unsigned int u[4]; } r;
  #pragma unroll
  for (int j=0;j<4;++j){
    float2 p2; p2.x = f[2*j]*s; p2.y = f[2*j+1]*s;
    __hip_bfloat162 p = __float22bfloat162_rn(p2);
    r.u[j] = *(unsigned int*)&p;
  }
  return r.s8;
}

// ---------------------------------------------------------------------------
// K0: pack wgb bf16: [0,64*4096) = w_g (same layout), [64*4096,65*4096) = w_bg
__global__ void k_packwg(const float* __restrict__ w_g,
                         const float* __restrict__ w_bg,
                         ushort_t* __restrict__ wgb){
  int i = blockIdx.x*256 + threadIdx.x;
  if (i >= 65*4096) return;
  float v = (i < 64*4096) ? w_g[i] : w_bg[i - 64*4096];
  wgb[i] = f2bf(v);
}

// ---------------------------------------------------------------------------
// K1: fused projection GEMM  Y = x @ Wcat^T + b   (M=2048, N=3840, K=768)
__global__ __launch_bounds__(256) void k_proj(
    const float* __restrict__ x,
    const float* __restrict__ w_qkv, const float* __restrict__ b_qkv,
    const float* __restrict__ w_local, const float* __restrict__ b_local,
    const float* __restrict__ w_global, const float* __restrict__ b_global,
    ushort_t* __restrict__ qb, ushort_t* __restrict__ kb, ushort_t* __restrict__ vb,
    ushort_t* __restrict__ lib, ushort_t* __restrict__ gib)
{
  __shared__ ushort_t As[64*40];
  __shared__ ushort_t Bs[64*40];
  const int n0 = blockIdx.x*64;
  const int m0 = blockIdx.y*64;
  const float* wsrc; const float* bsrc; int nb, seg;
  if (n0 < 2304){ wsrc=w_qkv;   bsrc=b_qkv;   nb=n0;      seg=0; }
  else if (n0 < 3072){ wsrc=w_local;  bsrc=b_local;  nb=n0-2304; seg=1; }
  else {               wsrc=w_global; bsrc=b_global; nb=n0-3072; seg=2; }
  const int t = threadIdx.x;
  const int w = t>>6, l = t&63;
  const int wr = w>>1, wc = w&1;
  const int rA = t>>2, cA = (t&3)*8;
  const int lr = l&15, lk = (l>>4)*8;
  f32x4 acc00={0,0,0,0}, acc01={0,0,0,0}, acc10={0,0,0,0}, acc11={0,0,0,0};
  for (int k0=0; k0<768; k0+=32){
    const float* xp = x    + (size_t)(m0+rA)*768 + k0 + cA;
    const float* wp = wsrc + (size_t)(nb+rA)*768 + k0 + cA;
    short8 ga = pack8(*(const f32x4*)(xp), *(const f32x4*)(xp+4));
    short8 gb = pack8(*(const f32x4*)(wp), *(const f32x4*)(wp+4));
    __syncthreads();
    *(short8*)(As + rA*40 + cA) = ga;
    *(short8*)(Bs + rA*40 + cA) = gb;
    __syncthreads();
    short8 a0 = *(const short8*)(As + (wr*32 +      lr)*40 + lk);
    short8 a1 = *(const short8*)(As + (wr*32 + 16 + lr)*40 + lk);
    short8 b0 = *(const short8*)(Bs + (wc*32 +      lr)*40 + lk);
    short8 b1 = *(const short8*)(Bs + (wc*32 + 16 + lr)*40 + lk);
    acc00 = __builtin_amdgcn_mfma_f32_16x16x32_bf16(a0,b0,acc00,0,0,0);
    acc01 = __builtin_amdgcn_mfma_f32_16x16x32_bf16(a0,b1,acc01,0,0,0);
    acc10 = __builtin_amdgcn_mfma_f32_16x16x32_bf16(a1,b0,acc10,0,0,0);
    acc11 = __builtin_amdgcn_mfma_f32_16x16x32_bf16(a1,b1,acc11,0,0,0);
  }
  #pragma unroll
  for (int fm=0; fm<2; ++fm){
    #pragma unroll
    for (int fn=0; fn<2; ++fn){
      f32x4 acc = (fm==0) ? ((fn==0)?acc00:acc01) : ((fn==0)?acc10:acc11);
      #pragma unroll
      for (int r=0; r<4; ++r){
        int grow = m0 + wr*32 + fm*16 + (l>>4)*4 + r;
        int colLoc = nb + wc*32 + fn*16 + lr;
        float val = acc[r] + bsrc[colLoc];
        int b = grow>>8, n = grow&255;
        if (seg==0){
          int s = colLoc/768, rr = colLoc - s*768;
          int h = rr>>6, d = rr&63;
          size_t idx = ((size_t)(b*12+h)*256 + n)*64 + d;
          if (s==0)      qb[idx] = f2bf(val*0.125f);
          else if (s==1) kb[idx] = f2bf(val);
          else           vb[idx] = f2bf(val);
        } else {
          int h = colLoc>>6, d = colLoc&63;
          size_t idx = ((size_t)(b*12+h)*256 + n)*64 + d;
          ushort_t gv = f2bf(gelu_exact(val));
          if (seg==1) lib[idx] = gv; else gib[idx] = gv;
        }
      }
    }
  }
}

// ---------------------------------------------------------------------------
// K2: transpose [bh][m][e] -> [bh][e][m] for v and gi
__global__ __launch_bounds__(256) void k_transpose(
    const ushort_t* __restrict__ vb, const ushort_t* __restrict__ gib,
    ushort_t* __restrict__ vT, ushort_t* __restrict__ giT)
{
  int bh = blockIdx.x;
  const ushort_t* src = blockIdx.y ? gib : vb;
  ushort_t* dst       = blockIdx.y ? giT : vT;
  __shared__ ushort_t tile[256*72];
  int t = threadIdx.x;
  for (int i=t; i<2048; i+=256){
    int m = i>>3, e0 = (i&7)*8;
    *(short8*)(tile + m*72 + e0) =
      *(const short8*)(src + ((size_t)bh*256 + m)*64 + e0);
  }
  __syncthreads();
  for (int i=t; i<2048; i+=256){
    int e = i>>5, m0 = (i&31)*8;
    short8 v;
    #pragma unroll
    for (int j=0;j<8;++j) v[j] = (short)tile[(m0+j)*72 + e];
    *(short8*)(dst + ((size_t)bh*64 + e)*256 + m0) = v;
  }
}

// ---------------------------------------------------------------------------
// K3a: S = q @ k^T (q pre-scaled), plus row max / row expsum
__global__ __launch_bounds__(256) void k_logits(
    const ushort_t* __restrict__ qb, const ushort_t* __restrict__ kb,
    float* __restrict__ S, float* __restrict__ rmaxb, float* __restrict__ rsumb)
{
  int bh = blockIdx.x, n0 = blockIdx.y*64;
  int t = threadIdx.x, w = t>>6, l = t&63;
  int lr = l&15, lk = (l>>4)*8;
  int row = n0 + w*16 + lr;
  const ushort_t* qp = qb + ((size_t)bh*256 + row)*64 + lk;
  short8 a0 = *(const short8*)(qp);
  short8 a1 = *(const short8*)(qp + 32);
  f32x4 acc[16];
  #pragma unroll
  for (int f=0; f<16; ++f) acc[f] = (f32x4){0,0,0,0};
  #pragma unroll
  for (int f=0; f<16; ++f){
    int col = f*16 + lr;
    const ushort_t* kp = kb + ((size_t)bh*256 + col)*64 + lk;
    short8 b0 = *(const short8*)(kp);
    short8 b1 = *(const short8*)(kp + 32);
    acc[f] = __builtin_amdgcn_mfma_f32_16x16x32_bf16(a0,b0,acc[f],0,0,0);
    acc[f] = __builtin_amdgcn_mfma_f32_16x16x32_bf16(a1,b1,acc[f],0,0,0);
  }
  #pragma unroll
  for (int r=0; r<4; ++r){
    int n = n0 + w*16 + (l>>4)*4 + r;
    float mx = acc[0][r];
    #pragma unroll
    for (int f=1; f<16; ++f) mx = fmaxf(mx, acc[f][r]);
    mx = fmaxf(mx, __shfl_xor(mx, 1));
    mx = fmaxf(mx, __shfl_xor(mx, 2));
    mx = fmaxf(mx, __shfl_xor(mx, 4));
    mx = fmaxf(mx, __shfl_xor(mx, 8));
    float sm = 0.f;
    #pragma unroll
    for (int f=0; f<16; ++f) sm += __expf(acc[f][r] - mx);
    sm += __shfl_xor(sm, 1);
    sm += __shfl_xor(sm, 2);
    sm += __shfl_xor(sm, 4);
    sm += __shfl_xor(sm, 8);
    #pragma unroll
    for (int f=0; f<16; ++f)
      S[((size_t)bh*256 + n)*256 + f*16 + lr] = acc[f][r];
    if (lr == 0){ rmaxb[bh*256+n] = mx; rsumb[bh*256+n] = sm; }
  }
}

// ---------------------------------------------------------------------------
// K3b: column stats over n for each m
__global__ __launch_bounds__(256) void k_colstats(
    const float* __restrict__ S, float* __restrict__ cmaxb, float* __restrict__ csumb)
{
  int bh = blockIdx.x, m0 = blockIdx.y*64;
  int t = threadIdx.x, q = t>>6, ml = t&63;
  int m = m0 + ml;
  float mx = -1e30f, sm = 0.f;
  for (int n=q*64; n<q*64+64; ++n){
    float v = S[((size_t)bh*256 + n)*256 + m];
    float nm = fmaxf(mx, v);
    sm = sm*__expf(mx-nm) + __expf(v-nm);
    mx = nm;
  }
  __shared__ float smx[4][64], ssm[4][64];
  smx[q][ml] = mx; ssm[q][ml] = sm;
  __syncthreads();
  if (t < 64){
    float M = smx[0][t];
    #pragma unroll
    for (int qq=1; qq<4; ++qq) M = fmaxf(M, smx[qq][t]);
    float Ssum = 0.f;
    #pragma unroll
    for (int qq=0; qq<4; ++qq) Ssum += ssm[qq][t]*__expf(smx[qq][t]-M);
    cmaxb[bh*256 + m0 + t] = M;
    csumb[bh*256 + m0 + t] = Ssum;
  }
}

// ---------------------------------------------------------------------------
// K3c: sa = attn @ v -> saf[B,N,C] (f32), gs = rattn @ gi -> gsb bf16
__global__ __launch_bounds__(256) void k_attnmm(
    const float* __restrict__ S,
    const float* __restrict__ rmaxb, const float* __restrict__ rsumb,
    const float* __restrict__ cmaxb, const float* __restrict__ csumb,
    const ushort_t* __restrict__ vT, const ushort_t* __restrict__ giT,
    ushort_t* __restrict__ gsb, float* __restrict__ saf)
{
  int bh = blockIdx.x, n0 = blockIdx.y*64;
  int b = bh/12, h = bh - b*12;
  int t = threadIdx.x, w = t>>6, l = t&63;
  int lr = l&15;
  int n = n0 + w*16 + lr;   // A-fragment row
  float rmx = rmaxb[bh*256 + n];
  f32x4 asa[4], ags[4];
  #pragma unroll
  for (int fn=0; fn<4; ++fn){ asa[fn]=(f32x4){0,0,0,0}; ags[fn]=(f32x4){0,0,0,0}; }
  #pragma unroll
  for (int kk=0; kk<8; ++kk){
    int mbase = kk*32 + (l>>4)*8;
    const float* Sp = S + ((size_t)bh*256 + n)*256 + mbase;
    f32x4 s_lo = *(const f32x4*)(Sp);
    f32x4 s_hi = *(const f32x4*)(Sp+4);
    f32x4 cm_lo = *(const f32x4*)(cmaxb + bh*256 + mbase);
    f32x4 cm_hi = *(const f32x4*)(cmaxb + bh*256 + mbase + 4);
    f32x4 cs_lo = *(const f32x4*)(csumb + bh*256 + mbase);
    f32x4 cs_hi = *(const f32x4*)(csumb + bh*256 + mbase + 4);
    short8 a_at, a_rat;
    #pragma unroll
    for (int j=0;j<4;++j){
      a_at[j]    = (short)f2bf(__expf(s_lo[j] - rmx));
      a_at[j+4]  = (short)f2bf(__expf(s_hi[j] - rmx));
      a_rat[j]   = (short)f2bf(__expf(s_lo[j] - cm_lo[j]) / cs_lo[j]);
      a_rat[j+4] = (short)f2bf(__expf(s_hi[j] - cm_hi[j]) / cs_hi[j]);
    }
    #pragma unroll
    for (int fn=0; fn<4; ++fn){
      int e = fn*16 + lr;
      short8 bv = *(const short8*)(vT  + ((size_t)bh*64 + e)*256 + mbase);
      short8 bg = *(const short8*)(giT + ((size_t)bh*64 + e)*256 + mbase);
      asa[fn] = __builtin_amdgcn_mfma_f32_16x16x32_bf16(a_at,  bv, asa[fn],0,0,0);
      ags[fn] = __builtin_amdgcn_mfma_f32_16x16x32_bf16(a_rat, bg, ags[fn],0,0,0);
    }
  }
  #pragma unroll
  for (int r=0; r<4; ++r){
    int nr = n0 + w*16 + (l>>4)*4 + r;
    float rs = rsumb[bh*256 + nr];
    #pragma unroll
    for (int fn=0; fn<4; ++fn){
      int e = fn*16 + lr;
      saf[((size_t)(b*256 + nr))*768 + h*64 + e] = asa[fn][r] / rs;
      gsb[((size_t)bh*256 + nr)*64 + e] = f2bf(ags[fn][r]);
    }
  }
}

// ---------------------------------------------------------------------------
// K4 v2: isa[n,e] = sum_d li[n,d]*(gi[n,:]@w_g[(d,e),:]) + gs[n,:]@w_bg[e,:]
// Per-d rank-1 A generation in registers; B (w_g d-slice) LDS-staged,
// XOR-swizzled; granule = 4 d-slices (32KB), double-buffered; 1 barrier/granule.
// Grid: 192 blocks x 4 waves; wave = 32 tokens x 64 outputs.
__global__ __launch_bounds__(256) void k_isa(
    const ushort_t* __restrict__ lib, const ushort_t* __restrict__ gib,
    const ushort_t* __restrict__ gsb, const ushort_t* __restrict__ wgb,
    float* __restrict__ isaf)
{
  __shared__ char smem[65536];   // 2 x 32KB granule buffers
  const int t = threadIdx.x, w = t>>6, l = t&63;
  const int lr = l&15, lk = l>>4;          // lk in 0..3
  const int t0 = blockIdx.x*128 + w*32;    // wave's first token
  const int inrow = lk*16;                 // base within-row byte (per k-half add ck*64)

  // Preload A-source fragments: gi as f32 (reused all 64 d), gs as bf16 (tail)
  float  gif[2][2][8];
  short8 gsf[2][2];
  #pragma unroll
  for (int mt=0; mt<2; ++mt){
    #pragma unroll
    for (int ck=0; ck<2; ++ck){
      const size_t rowoff = (size_t)(t0 + mt*16 + lr)*64 + ck*32 + lk*8;
      short8 gv = *(const short8*)(gib + rowoff);
      #pragma unroll
      for (int j=0;j<8;++j) gif[mt][ck][j] = bf2f((ushort_t)gv[j]);
      gsf[mt][ck] = *(const short8*)(gsb + rowoff);
    }
  }
  const size_t liRow0 = (size_t)(t0 +      lr)*64;
  const size_t liRow1 = (size_t)(t0 + 16 + lr)*64;

  f32x4 acc[2][4];
  #pragma unroll
  for (int mt=0; mt<2; ++mt)
    #pragma unroll
    for (int et=0; et<4; ++et) acc[mt][et] = (f32x4){0,0,0,0};

  // ---- staging helpers (reg-staged, swizzled ds_write) ----
  short8 stg[8];
  // prologue: load+write granule 0 into buf0
  {
    const char* src = (const char*)wgb;
    #pragma unroll
    for (int i=0;i<8;++i) stg[i] = *(const short8*)(src + (i*256 + t)*16);
    #pragma unroll
    for (int i=0;i<8;++i){
      int L = (i*256 + t)*16, R = L>>7, WB = L&127;
      *(short8*)(smem + R*128 + (WB ^ ((R&7)<<4))) = stg[i];
    }
  }
  __syncthreads();

  for (int g=0; g<16; ++g){
    // issue loads for granule g+1 (overlaps compute below)
    const char* src = (const char*)wgb + (size_t)(g+1)*32768;
    #pragma unroll
    for (int i=0;i<8;++i) stg[i] = *(const short8*)(src + (i*256 + t)*16);

    // compute granule g (4 d-slices) from buf[g&1]
    const char* buf = smem + (g&1)*32768;
    #pragma unroll
    for (int dd=0; dd<4; ++dd){
      const int d = g*4 + dd;
      // B fragments (swizzled reads)
      short8 bfr[4][2];
      #pragma unroll
      for (int et=0; et<4; ++et){
        const int e = et*16 + lr;
        const int sw = (e&7)<<4;
        #pragma unroll
        for (int ck=0; ck<2; ++ck)
          bfr[et][ck] = *(const short8*)(buf + dd*8192 + e*128 + ((ck*64 + inrow) ^ sw));
      }
      // A fragments: li[row,d] * gi-frag
      const float lv0 = bf2f(lib[liRow0 + d]);
      const float lv1 = bf2f(lib[liRow1 + d]);
      short8 au0[2], au1[2];
      #pragma unroll
      for (int ck=0; ck<2; ++ck){
        au0[ck] = mulpack8(gif[0][ck], lv0);
        au1[ck] = mulpack8(gif[1][ck], lv1);
      }
      #pragma unroll
      for (int ck=0; ck<2; ++ck)
        #pragma unroll
        for (int et=0; et<4; ++et){
          acc[0][et] = __builtin_amdgcn_mfma_f32_16x16x32_bf16(au0[ck], bfr[et][ck], acc[0][et],0,0,0);
          acc[1][et] = __builtin_amdgcn_mfma_f32_16x16x32_bf16(au1[ck], bfr[et][ck], acc[1][et],0,0,0);
        }
    }

    // write staged granule g+1 into buf[(g+1)&1], then barrier
    char* dbuf = smem + ((g+1)&1)*32768;
    #pragma unroll
    for (int i=0;i<8;++i){
      int L = (i*256 + t)*16, R = L>>7, WB = L&127;
      *(short8*)(dbuf + R*128 + (WB ^ ((R&7)<<4))) = stg[i];
    }
    __syncthreads();
  }

  // tail: d=64 (bias via gs @ w_bg^T), granule 16 sits in buf[0], dd=0
  {
    const char* buf = smem;  // (16&1)==0
    #pragma unroll
    for (int et=0; et<4; ++et){
      const int e = et*16 + lr;
      const int sw = (e&7)<<4;
      #pragma unroll
      for (int ck=0; ck<2; ++ck){
        short8 bfr = *(const short8*)(buf + e*128 + ((ck*64 + inrow) ^ sw));
        acc[0][et] = __builtin_amdgcn_mfma_f32_16x16x32_bf16(gsf[0][ck], bfr, acc[0][et],0,0,0);
        acc[1][et] = __builtin_amdgcn_mfma_f32_16x16x32_bf16(gsf[1][ck], bfr, acc[1][et],0,0,0);
      }
    }
  }

  // epilogue: C/D layout col=l&15, row=(l>>4)*4+r
  #pragma unroll
  for (int mt=0; mt<2; ++mt){
    #pragma unroll
    for (int et=0; et<4; ++et){
      #pragma unroll
      for (int r=0; r<4; ++r){
        int tok = t0 + mt*16 + lk*4 + r;
        int e = et*16 + lr;
        int bh = tok>>8, n = tok&255;
        int b = bh/12, h = bh - b*12;
        isaf[((size_t)(b*256 + n))*768 + h*64 + e] = acc[mt][et][r];
      }
    }
  }
}

// ---------------------------------------------------------------------------
// K5: per-token LayerNorm(sa), LayerNorm(isa), gated mix -> zb bf16
__global__ __launch_bounds__(256) void k_lnmix(
    const float* __restrict__ saf, const float* __restrict__ isaf,
    const float* __restrict__ lam, ushort_t* __restrict__ zb)
{
  int tok = blockIdx.x*4 + (threadIdx.x>>6);
  int l = threadIdx.x & 63;
  float g = 1.f/(1.f + __expf(-lam[0]));
  const float* sp = saf  + (size_t)tok*768;
  const float* ip = isaf + (size_t)tok*768;
  float sv[12], iv[12];
  float s1=0.f, s2=0.f, i1=0.f, i2=0.f;
  #pragma unroll
  for (int j=0;j<12;++j){
    sv[j] = sp[l + j*64];  s1 += sv[j];  s2 += sv[j]*sv[j];
    iv[j] = ip[l + j*64];  i1 += iv[j];  i2 += iv[j]*iv[j];
  }
  #pragma unroll
  for (int m=1; m<64; m<<=1){
    s1 += __shfl_xor(s1, m); s2 += __shfl_xor(s2, m);
    i1 += __shfl_xor(i1, m); i2 += __shfl_xor(i2, m);
  }
  float smean = s1*(1.f/768.f), svar = s2*(1.f/768.f) - smean*smean;
  float imean = i1*(1.f/768.f), ivar = i2*(1.f/768.f) - imean*imean;
  float sinv = 1.f/sqrtf(svar + 1e-5f);
  float iinv = 1.f/sqrtf(ivar + 1e-5f);
  #pragma unroll
  for (int j=0;j<12;++j){
    float z = g*(sv[j]-smean)*sinv + (1.f-g)*(iv[j]-imean)*iinv;
    zb[(size_t)tok*768 + l + j*64] = f2bf(z);
  }
}

// ---------------------------------------------------------------------------
// K6: out = z @ w_proj^T + b_proj  (M=2048, N=768, K=768) -> f32 out
__global__ __launch_bounds__(256) void k_outproj(
    const ushort_t* __restrict__ zb, const float* __restrict__ wproj,
    const float* __restrict__ bproj, float* __restrict__ out)
{
  __shared__ ushort_t As[64*40];
  __shared__ ushort_t Bs[64*40];
  const int n0 = blockIdx.x*64;
  const int m0 = blockIdx.y*64;
  const int t = threadIdx.x, w = t>>6, l = t&63;
  const int wr = w>>1, wc = w&1;
  const int rA = t>>2, cA = (t&3)*8;
  const int lr = l&15, lk = (l>>4)*8;
  f32x4 acc00={0,0,0,0}, acc01={0,0,0,0}, acc10={0,0,0,0}, acc11={0,0,0,0};
  for (int k0=0; k0<768; k0+=32){
    short8 ga = *(const short8*)(zb + (size_t)(m0+rA)*768 + k0 + cA);
    const float* wp = wproj + (size_t)(n0+rA)*768 + k0 + cA;
    short8 gb = pack8(*(const f32x4*)(wp), *(const f32x4*)(wp+4));
    __syncthreads();
    *(short8*)(As + rA*40 + cA) = ga;
    *(short8*)(Bs + rA*40 + cA) = gb;
    __syncthreads();
    short8 a0 = *(const short8*)(As + (wr*32 +      lr)*40 + lk);
    short8 a1 = *(const short8*)(As + (wr*32 + 16 + lr)*40 + lk);
    short8 b0 = *(const short8*)(Bs + (wc*32 +      lr)*40 + lk);
    short8 b1 = *(const short8*)(Bs + (wc*32 + 16 + lr)*40 + lk);
    acc00 = __builtin_amdgcn_mfma_f32_16x16x32_bf16(a0,b0,acc00,0,0,0);
    acc01 = __builtin_amdgcn_mfma_f32_16x16x32_bf16(a0,b1,acc01,0,0,0);
    acc10 = __builtin_amdgcn_mfma_f32_16x16x32_bf16(a1,b0,acc10,0,0,0);
    acc11 = __builtin_amdgcn_mfma_f32_16x16x32_bf16(a1,b1,acc11,0,0,0);
  }
  #pragma unroll
  for (int fm=0; fm<2; ++fm){
    #pragma unroll
    for (int fn=0; fn<2; ++fn){
      f32x4 acc = (fm==0) ? ((fn==0)?acc00:acc01) : ((fn==0)?acc10:acc11);
      #pragma unroll
      for (int r=0; r<4; ++r){
        int grow = m0 + wr*32 + fm*16 + (l>>4)*4 + r;
        int gcol = n0 + wc*32 + fn*16 + lr;
        out[(size_t)grow*768 + gcol] = acc[r] + bproj[gcol];
      }
    }
  }
}

// ---------------------------------------------------------------------------
extern "C" void kernel_launch(void* const* d_in, const int* in_sizes, int n_in,
                              void* d_out, int out_size, void* d_ws, size_t ws_size,
                              hipStream_t stream)
{
  const float* x        = (const float*)d_in[0];
  const float* w_qkv    = (const float*)d_in[1];
  const float* b_qkv    = (const float*)d_in[2];
  const float* w_g      = (const float*)d_in[3];
  const float* w_bg     = (const float*)d_in[4];
  const float* w_local  = (const float*)d_in[5];
  const float* b_local  = (const float*)d_in[6];
  const float* w_globalp= (const float*)d_in[7];
  const float* b_globalp= (const float*)d_in[8];
  const float* lam      = (const float*)d_in[9];
  const float* w_proj   = (const float*)d_in[10];
  const float* b_proj   = (const float*)d_in[11];
  float* out = (float*)d_out;

  char* p = (char*)d_ws;
  auto alloc = [&](size_t bytes)->char*{
    char* r = p; p += (bytes + 255) & ~(size_t)255; return r;
  };
  // Live-range-aware layout (peak ~49 MB):
  ushort_t* wgb = (ushort_t*)alloc((size_t)68*4096*2);  // 65 used + 3 pad slices
  ushort_t* qb  = (ushort_t*)alloc((size_t)THW*64*2);   // dead after k_logits
  ushort_t* kb  = (ushort_t*)alloc((size_t)THW*64*2);   // dead after k_logits
  ushort_t* vb  = (ushort_t*)alloc((size_t)THW*64*2);   // dead after k_transpose
  ushort_t* vT  = (ushort_t*)alloc((size_t)THW*64*2);   // dead after k_attnmm
  ushort_t* giT = (ushort_t*)alloc((size_t)THW*64*2);   // dead after k_attnmm
  ushort_t* gib = (ushort_t*)alloc((size_t)THW*64*2);
  ushort_t* lib = (ushort_t*)alloc((size_t)THW*64*2);
  ushort_t* gsb = (ushort_t*)alloc((size_t)THW*64*2);
  float*  S     = (float*)  alloc((size_t)BH*256*256*4);
  float*  rmaxb = (float*)  alloc((size_t)BH*256*4);
  float*  rsumb = (float*)  alloc((size_t)BH*256*4);
  float*  cmaxb = (float*)  alloc((size_t)BH*256*4);
  float*  csumb = (float*)  alloc((size_t)BH*256*4);
  // Aliases over dead buffers:
  float*    saf  = (float*)qb;      // 6.29 MB over qb+kb (contiguous)
  float*    isaf = (float*)vT;      // 6.29 MB over vT+giT (contiguous)
  ushort_t* zb   = (ushort_t*)vb;   // 3.15 MB over vb

  hipLaunchKernelGGL(k_packwg, dim3((65*4096+255)/256), dim3(256), 0, stream,
                     w_g, w_bg, wgb);
  hipLaunchKernelGGL(k_proj, dim3(60,32), dim3(256), 0, stream,
                     x, w_qkv, b_qkv, w_local, b_local, w_globalp, b_globalp,
                     qb, kb, vb, lib, gib);
  hipLaunchKernelGGL(k_transpose, dim3(96,2), dim3(256), 0, stream,
                     vb, gib, vT, giT);
  hipLaunchKernelGGL(k_logits, dim3(96,4), dim3(256), 0, stream,
                     qb, kb, S, rmaxb, rsumb);
  hipLaunchKernelGGL(k_colstats, dim3(96,4), dim3(256), 0, stream,
                     S, cmaxb, csumb);
  hipLaunchKernelGGL(k_attnmm, dim3(96,4), dim3(256), 0, stream,
                     S, rmaxb, rsumb, cmaxb, csumb, vT, giT, gsb, saf);
  hipLaunchKernelGGL(k_isa, dim3(192), dim3(256), 0, stream,
                     lib, gib, gsb, wgb, isaf);
  hipLaunchKernelGGL(k_lnmix, dim3(512), dim3(256), 0, stream,
                     saf, isaf, lam, zb);
  hipLaunchKernelGGL(k_outproj, dim3(12,32), dim3(256), 0, stream,
                     zb, w_proj, b_proj, out);
}